// Round 15
// baseline (2058.459 us; speedup 1.0000x reference)
//
#include <hip/hip_runtime.h>
#include <hip/hip_bf16.h>

#define NN 50000
#define EE 1600000
#define FF 384
#define MPAD 50048
#define NITER 5
#define EPB 6250      // edges per block in bucket_scatter
#define BCAP 220000   // bucket capacity (mean 200000, +47 sigma)
#define GRP 6250      // rows per dst-group (NN/8)
#define RBLK4 12500   // blocks per pass (4 rows/block, 1 row/wave)
#define NSLICE 12
#define SLABB 3203072   // bytes per slab = MPAD*64
#define SLABW 800768    // u32 per slab = MPAD*16

typedef unsigned int u32;
typedef unsigned short u16;
typedef __attribute__((ext_vector_type(8))) short short8;
typedef __attribute__((ext_vector_type(4))) float f32x4;

typedef const __attribute__((address_space(1))) void* gptr_t;
typedef __attribute__((address_space(3))) void* lptr_t;

__device__ __forceinline__ float bf_lo(u32 u) {
  u32 v = u << 16;
  return __builtin_bit_cast(float, v);
}
__device__ __forceinline__ float bf_hi(u32 u) {
  u32 v = u & 0xFFFF0000u;
  return __builtin_bit_cast(float, v);
}
__device__ __forceinline__ u32 f2bf(float f) {  // RNE f32 -> bf16 bits
  u32 u = __builtin_bit_cast(u32, f);
  return (u + 0x7FFFu + ((u >> 16) & 1u)) >> 16;
}
__device__ __forceinline__ u32 pack2(float lo, float hi) {
  return f2bf(lo) | (f2bf(hi) << 16);
}
__device__ __forceinline__ void load16_lds(const void* g, void* l) {
  __builtin_amdgcn_global_load_lds((gptr_t)g, (lptr_t)l, 16, 0, 0);
}

// ---------------- setup (atomic-free CSR build; r13 verified) ----------------
__global__ void init_bcur_kernel(int* __restrict__ bcur) {
  if (threadIdx.x < 8) bcur[threadIdx.x] = threadIdx.x * BCAP;
}

__global__ __launch_bounds__(256) void bucket_scatter_kernel(
    const int* __restrict__ src, const int* __restrict__ dst,
    int* __restrict__ bcur, int* __restrict__ es_src, int* __restrict__ es_dst) {
  __shared__ int osrc[EPB];
  __shared__ int odst[EPB];
  __shared__ int h[8], lo8[8], gbase[8], c2[8];
  const int t = threadIdx.x;
  if (t < 8) { h[t] = 0; c2[t] = 0; }
  __syncthreads();
  const int e0 = blockIdx.x * EPB;
  for (int i = t; i < EPB; i += 256) {
    int d = dst[e0 + i];
    atomicAdd(&h[d / GRP], 1);
  }
  __syncthreads();
  if (t == 0) { int r = 0; for (int b = 0; b < 8; ++b) { lo8[b] = r; r += h[b]; } }
  __syncthreads();
  if (t < 8) gbase[t] = atomicAdd(&bcur[t], h[t]);
  __syncthreads();
  for (int i = t; i < EPB; i += 256) {
    int s = src[e0 + i], d = dst[e0 + i];
    int b = d / GRP;
    int p = lo8[b] + atomicAdd(&c2[b], 1);
    osrc[p] = s; odst[p] = d;
  }
  __syncthreads();
  for (int i = t; i < EPB; i += 256) {
    int b = 0;
    while (b < 7 && i >= lo8[b + 1]) ++b;
    int g = gbase[b] + (i - lo8[b]);
    es_src[g] = osrc[i];
    es_dst[g] = odst[i];
  }
}

__global__ __launch_bounds__(256) void hist_part_kernel(
    const int* __restrict__ es_dst, const int* __restrict__ bcur,
    int* __restrict__ part) {
  __shared__ int h[GRP];
  const int g = blockIdx.x >> 5;
  const int s = blockIdx.x & 31;
  const int lo = g * GRP;
  const int base = g * BCAP;
  const int n = bcur[g] - base;
  const int chunk = (n + 31) >> 5;
  const int i0 = s * chunk;
  int i1 = i0 + chunk; if (i1 > n) i1 = n;
  for (int i = threadIdx.x; i < GRP; i += 256) h[i] = 0;
  __syncthreads();
  for (int i = i0 + threadIdx.x; i < i1; i += 256)
    atomicAdd(&h[es_dst[base + i] - lo], 1);  // LDS atomic
  __syncthreads();
  int* po = part + (size_t)blockIdx.x * GRP;
  for (int i = threadIdx.x; i < GRP; i += 256) po[i] = h[i];
}

__global__ void reduce_kernel(int* __restrict__ part, int* __restrict__ cnt) {
  int r = blockIdx.x * 256 + threadIdx.x;
  if (r >= NN) return;
  int g = r / GRP, o = r - g * GRP;
  int* p = part + (size_t)(g * 32) * GRP + o;
  int run = 0;
#pragma unroll
  for (int s = 0; s < 32; ++s) {
    int v = p[(size_t)s * GRP];
    p[(size_t)s * GRP] = run;
    run += v;
  }
  cnt[r] = run;
}

__global__ void scan_kernel(const int* __restrict__ cnt, int* __restrict__ row_start) {
  __shared__ int wsum[4];
  const int CH = 196;
  int t = threadIdx.x;
  int lo = t * CH;
  int hi = lo + CH; if (hi > NN) hi = NN;
  int s = 0;
  int n4 = (hi - lo) >> 2;
  const int4* p = (const int4*)(cnt + lo);
  for (int i = 0; i < n4; ++i) { int4 c = p[i]; s += c.x + c.y + c.z + c.w; }
  int lane = t & 63, w = t >> 6;
  int v = s;
  for (int d = 1; d < 64; d <<= 1) { int u = __shfl_up(v, d, 64); if (lane >= d) v += u; }
  if (lane == 63) wsum[w] = v;
  __syncthreads();
  int run = v - s;
  for (int i = 0; i < w; ++i) run += wsum[i];
  int4* q1 = (int4*)(row_start + lo);
  for (int k = 0; k < n4; ++k) {
    int4 c = p[k];
    int4 o; o.x = run; o.y = run + c.x; o.z = o.y + c.y; o.w = o.z + c.z;
    run = o.w + c.w;
    q1[k] = o;
  }
  if (hi == NN && lo < NN) row_start[NN] = run;
}

__global__ __launch_bounds__(256) void scatter4_kernel(
    const int* __restrict__ es_src, const int* __restrict__ es_dst,
    const int* __restrict__ bcur, const int* __restrict__ row_start,
    const int* __restrict__ part, int* __restrict__ col) {
  __shared__ int cur[GRP];
  const int g = blockIdx.x >> 5;
  const int s = blockIdx.x & 31;
  const int lo = g * GRP;
  const int base = g * BCAP;
  const int n = bcur[g] - base;
  const int chunk = (n + 31) >> 5;
  const int i0 = s * chunk;
  int i1 = i0 + chunk; if (i1 > n) i1 = n;
  const int* po = part + (size_t)blockIdx.x * GRP;
  for (int i = threadIdx.x; i < GRP; i += 256)
    cur[i] = row_start[lo + i] + po[i];
  __syncthreads();
  for (int i = i0 + threadIdx.x; i < i1; i += 256) {
    int d = es_dst[base + i];
    int p = atomicAdd(&cur[d - lo], 1);  // LDS atomic
    col[p] = es_src[base + i];
  }
}

// ---------------- converts ----------------
// Slice-major: X[s][row][16 u32], slab stride SLABW u32. u32 col j -> slab j>>4, off j&15.
__global__ void convert_x_kernel(const float* __restrict__ xin, u32* __restrict__ xp) {
  size_t i = ((size_t)blockIdx.x * 256 + threadIdx.x) * 4;  // f32 index
  if (i >= (size_t)NN * FF) return;
  float4 f = *(const float4*)(xin + i);
  int row = (int)(i / FF);
  int c = (int)(i - (size_t)row * FF);
  int j = c >> 1;                    // even u32 col
  u32* q = xp + (size_t)(j >> 4) * SLABW + (size_t)row * 16 + (j & 15);
  q[0] = pack2(f.x, f.y);
  q[1] = pack2(f.z, f.w);           // j&15 <= 14, same slab
}

// zero pad rows 50000..50047 in all 12 slabs of agg, x0, x1
__global__ void zero_pad_kernel(u32* __restrict__ a0, u32* __restrict__ a1,
                                u32* __restrict__ a2) {
  int i = blockIdx.x * 256 + threadIdx.x;  // < 12*48*16 = 9216
  if (i >= 9216) return;
  int s = i / 768, rem = i - s * 768;
  size_t addr = (size_t)s * SLABW + (size_t)(NN + rem / 16) * 16 + (rem & 15);
  a0[addr] = 0; a1[addr] = 0; a2[addr] = 0;
}

// Bt[n][k] (384 x 768 bf16, row-major): k<384 -> W_rel[n][k], else W_root[n][k-384]
__global__ void build_bt_kernel(const float* __restrict__ Wr, const float* __restrict__ Wt,
                                u16* __restrict__ Bt) {
  int i = blockIdx.x * 256 + threadIdx.x;
  if (i >= FF * 2 * FF) return;
  int n = i / (2 * FF);
  int k = i - n * (2 * FF);
  float v = (k < FF) ? Wr[n * FF + k] : Wt[n * FF + (k - FF)];
  Bt[i] = (u16)f2bf(v);
}

// ---------------- SpMM: agg[dst] = sum_src x[src], 12 slice-major passes ----------------
// One ROW per WAVE. Lane quarter q = lane>>4 owns edge j+q: col[j+q] loaded
// directly (16 lanes same addr -> HW broadcast, NO shfl), gathers its 4B from
// the L2-resident 3.2MB slab. 16-edge unroll = 4 gathers in flight. Final
// cross-quarter reduce: 2 shfl_down + adds. agg NT-stored (64B/wave).
__global__ __launch_bounds__(256) void spmm12_kernel(
    const u32* __restrict__ xp, const int* __restrict__ rs,
    const int* __restrict__ col, u32* __restrict__ agg) {
  const int pass = blockIdx.x / RBLK4;
  const int rb = blockIdx.x - pass * RBLK4;
  const int lane = threadIdx.x & 63;
  const int q = lane >> 4;   // edge slot 0..3
  const int sl = lane & 15;  // u32 column within slab row
  const int r = rb * 4 + (threadIdx.x >> 6);  // < 50000 exactly

  const int j0 = rs[r], j1 = rs[r + 1];
  const u32* xw = xp + (size_t)pass * SLABW + sl;
  float alo = 0.f, ahi = 0.f;

  int j = j0;
  for (; j + 16 <= j1; j += 16) {
    int c0 = __builtin_nontemporal_load(col + j + q);
    int c1 = __builtin_nontemporal_load(col + j + 4 + q);
    int c2 = __builtin_nontemporal_load(col + j + 8 + q);
    int c3 = __builtin_nontemporal_load(col + j + 12 + q);
    u32 u0 = xw[(size_t)c0 * 16];
    u32 u1 = xw[(size_t)c1 * 16];
    u32 u2 = xw[(size_t)c2 * 16];
    u32 u3 = xw[(size_t)c3 * 16];
    alo += bf_lo(u0) + bf_lo(u1) + bf_lo(u2) + bf_lo(u3);
    ahi += bf_hi(u0) + bf_hi(u1) + bf_hi(u2) + bf_hi(u3);
  }
  for (; j < j1; j += 4) {
    if (j + q < j1) {
      int c0 = __builtin_nontemporal_load(col + j + q);
      u32 u0 = xw[(size_t)c0 * 16];
      alo += bf_lo(u0); ahi += bf_hi(u0);
    }
  }
  alo += __shfl_down(alo, 32, 64); ahi += __shfl_down(ahi, 32, 64);
  alo += __shfl_down(alo, 16, 64); ahi += __shfl_down(ahi, 16, 64);
  if (lane < 16)
    __builtin_nontemporal_store(pack2(alo, ahi),
                                agg + (size_t)pass * SLABW + (size_t)r * 16 + sl);
}

// ---------------- GEMM: Xout = relu([agg | x] @ Bt^T), slice-major A/C ----------------
// BM=64, BN=384. 512 thr = 8 waves (2m x 4n), wave tile 32x96, acc[2][6].
// A k-tile kt = slabs {2kt, 2kt+1} 64B rows; staged via global_load_lds w16 with
// the XOR swizzle applied across the logical 128B row (split over 2 slabs).
// B: LDS single 48KB. grid 782, bijective XCD swizzle.
__global__ __launch_bounds__(512, 4) void gemm_kernel(
    const u16* __restrict__ Aagg, const u16* __restrict__ Ax,
    const u16* __restrict__ Bt, u16* __restrict__ Xout) {
  __shared__ __align__(16) u16 As[2][64 * 64];
  __shared__ __align__(16) u16 Bs[384 * 64];

  // bijective XCD swizzle: nwg=782, q=97, r=6
  const int orig = blockIdx.x;
  const int xcd = orig & 7, idx = orig >> 3;
  const int wg = ((xcd < 6) ? xcd * 98 : 6 * 98 + (xcd - 6) * 97) + idx;
  const int m0 = wg * 64;

  const int tid = threadIdx.x;
  const int lane = tid & 63;
  const int w = tid >> 6;
  const int wr = w >> 2;
  const int wc = w & 3;

  f32x4 acc[2][6] = {};

#define STAGE_A(KT, BUF)                                                        \
  {                                                                             \
    const u16* base_ = ((KT) < 6) ? Aagg : Ax;                                  \
    const int sl2_ = (((KT) < 6) ? (KT) : (KT)-6) * 2;                          \
    const int rA_ = tid >> 3;                                                   \
    const int bp_ = ((tid & 7) << 4) ^ ((rA_ & 7) << 4);                        \
    load16_lds((const char*)base_ + (size_t)(sl2_ + (bp_ >> 6)) * SLABB +       \
                   (size_t)(m0 + rA_) * 64 + (bp_ & 63),                        \
               (char*)&As[BUF][0] + tid * 16);                                  \
  }

#define STAGE_B(KT)                                                             \
  {                                                                             \
    const int kbB_ = (KT) << 7;                                                 \
    _Pragma("unroll")                                                           \
    for (int i = 0; i < 6; ++i) {                                               \
      const int c = tid + i * 512;                                              \
      const int rB_ = c >> 3;                                                   \
      const int bcB_ = (c & 7) << 4;                                            \
      load16_lds((const char*)Bt + (size_t)rB_ * 1536 + kbB_ +                  \
                     (bcB_ ^ ((rB_ & 7) << 4)),                                 \
                 (char*)&Bs[0] + c * 16);                                       \
    }                                                                           \
  }

  STAGE_A(0, 0);
  STAGE_B(0);
  __syncthreads();

  int buf = 0;
  for (int kt = 0; kt < 12; ++kt) {
    if (kt < 11) STAGE_A(kt + 1, buf ^ 1);
#pragma unroll
    for (int ks = 0; ks < 2; ++ks) {
      short8 af[2], bfm[6];
#pragma unroll
      for (int ni = 0; ni < 6; ++ni) {
        const int r = wc * 96 + ni * 16 + (lane & 15);
        const int bc = (ks * 64 + ((lane >> 4) << 4)) ^ ((r & 7) << 4);
        bfm[ni] = *(const short8*)((const char*)&Bs[0] + r * 128 + bc);
      }
#pragma unroll
      for (int mi = 0; mi < 2; ++mi) {
        const int r = wr * 32 + mi * 16 + (lane & 15);
        const int bc = (ks * 64 + ((lane >> 4) << 4)) ^ ((r & 7) << 4);
        af[mi] = *(const short8*)((const char*)&As[buf][0] + r * 128 + bc);
      }
#pragma unroll
      for (int mi = 0; mi < 2; ++mi)
#pragma unroll
        for (int ni = 0; ni < 6; ++ni)
          acc[mi][ni] = __builtin_amdgcn_mfma_f32_16x16x32_bf16(af[mi], bfm[ni], acc[mi][ni], 0, 0, 0);
    }
    __syncthreads();
    if (kt < 11) {
      STAGE_B(kt + 1);
      __syncthreads();
    }
    buf ^= 1;
  }

  // epilogue: relu -> bf16, slice-major C write. u16 col c -> slab c>>5, off c&31.
#pragma unroll
  for (int mi = 0; mi < 2; ++mi) {
#pragma unroll
    for (int r = 0; r < 4; ++r) {
      const int row = m0 + wr * 32 + mi * 16 + ((lane >> 4) << 2) + r;
#pragma unroll
      for (int ni = 0; ni < 6; ++ni) {
        const int c = wc * 96 + ni * 16 + (lane & 15);
        float v = fmaxf(acc[mi][ni][r], 0.0f);
        Xout[(size_t)(c >> 5) * (SLABB / 2) + (size_t)row * 32 + (c & 31)] =
            (u16)f2bf(v);
      }
    }
  }
#undef STAGE_A
#undef STAGE_B
}

// ---------------- readout: out[n] = dot(x[n,:], W_lin), slice-major ----------------
__global__ void readout_kernel(const u32* __restrict__ xp, const float* __restrict__ wl,
                               float* __restrict__ out) {
  int row = blockIdx.x * 4 + (threadIdx.x >> 6);
  int lane = threadIdx.x & 63;
  if (row >= NN) return;
  float s = 0.f;
#pragma unroll
  for (int k = 0; k < 3; ++k) {
    const int sb = k * 4 + (lane >> 4);
    u32 u = xp[(size_t)sb * SLABW + (size_t)row * 16 + (lane & 15)];
    const int f = 2 * (64 * k + lane);
    s += bf_lo(u) * wl[f] + bf_hi(u) * wl[f + 1];
  }
#pragma unroll
  for (int off = 32; off > 0; off >>= 1) s += __shfl_down(s, off, 64);
  if (lane == 0) out[row] = s;
}

extern "C" void kernel_launch(void* const* d_in, const int* in_sizes, int n_in,
                              void* d_out, int out_size, void* d_ws, size_t ws_size,
                              hipStream_t stream) {
  const float* x_in = (const float*)d_in[0];
  const int* ei = (const int*)d_in[1];
  const float* W_rel = (const float*)d_in[3];
  const float* W_root = (const float*)d_in[4];
  const float* W_lin = (const float*)d_in[5];
  float* out = (float*)d_out;

  char* ws = (char*)d_ws;
  int* cnt = (int*)(ws);                      // 200,000 B used (+64 spare)
  int* bcur = cnt + NN;                       // 8 ints in the spare
  int* row_start = (int*)(ws + 200064);       // 200,064 B
  int* col = (int*)(ws + 600192);             // 6,400,000 B
  u16* Bt = (u16*)(ws + 7000192);             // 589,824 B
  u16* agg = (u16*)(ws + 7590016);            // 38,436,864 B (12 slabs)
  u16* x0 = (u16*)(ws + 46026880);            // 38,436,864 B
  u16* x1 = (u16*)(ws + 84463744);            // 38,436,864 B
  if (ws_size < (size_t)122900608) return;    // need ~117 MB
  // transient setup arrays overlay agg (dead before first spmm write):
  int* es_src = (int*)(ws + 7590016);               // 7,040,000 B
  int* es_dst = (int*)(ws + 7590016 + 7040000);     // 7,040,000 B
  int* part = (int*)(ws + 7590016 + 14080000);      // 6,400,000 B

  const int* esrc = ei;
  const int* edst = ei + EE;

  init_bcur_kernel<<<1, 64, 0, stream>>>(bcur);
  bucket_scatter_kernel<<<EE / EPB, 256, 0, stream>>>(esrc, edst, bcur, es_src, es_dst);
  hist_part_kernel<<<256, 256, 0, stream>>>(es_dst, bcur, part);
  reduce_kernel<<<(NN + 255) / 256, 256, 0, stream>>>(part, cnt);
  scan_kernel<<<1, 256, 0, stream>>>(cnt, row_start);
  scatter4_kernel<<<256, 256, 0, stream>>>(es_src, es_dst, bcur, row_start, part, col);
  convert_x_kernel<<<(NN * FF / 4 + 255) / 256, 256, 0, stream>>>(x_in, (u32*)x0);
  build_bt_kernel<<<(FF * 2 * FF + 255) / 256, 256, 0, stream>>>(W_rel, W_root, Bt);
  // after scatter4: agg overlay dead -> zero pad rows of all three slice-major arrays
  zero_pad_kernel<<<36, 256, 0, stream>>>((u32*)agg, (u32*)x0, (u32*)x1);

  u16* xs = x0;
  u16* xd = x1;
  for (int t = 0; t < NITER; ++t) {
    spmm12_kernel<<<NSLICE * RBLK4, 256, 0, stream>>>((const u32*)xs, row_start, col, (u32*)agg);
    gemm_kernel<<<782, 512, 0, stream>>>(agg, xs, Bt, xd);
    u16* tmp = xs; xs = xd; xd = tmp;
  }
  readout_kernel<<<NN / 4, 256, 0, stream>>>((const u32*)xs, W_lin, out);
}

// Round 16
// 1262.534 us; speedup vs baseline: 1.6304x; 1.6304x over previous
//
#include <hip/hip_runtime.h>
#include <hip/hip_bf16.h>

#define NN 50000
#define EE 1600000
#define FF 384
#define MPAD 50048
#define NITER 5
#define EPB 6250      // edges per block in bucket_scatter
#define BCAP 220000   // bucket capacity (mean 200000, +47 sigma)
#define GRP 6250      // rows per dst-group (NN/8)

typedef unsigned int u32;
typedef unsigned short u16;
typedef __attribute__((ext_vector_type(8))) short short8;
typedef __attribute__((ext_vector_type(4))) float f32x4;

typedef const __attribute__((address_space(1))) void* gptr_t;
typedef __attribute__((address_space(3))) void* lptr_t;

__device__ __forceinline__ float bf_lo(u32 u) {
  u32 v = u << 16;
  return __builtin_bit_cast(float, v);
}
__device__ __forceinline__ float bf_hi(u32 u) {
  u32 v = u & 0xFFFF0000u;
  return __builtin_bit_cast(float, v);
}
__device__ __forceinline__ u32 f2bf(float f) {  // RNE f32 -> bf16 bits
  u32 u = __builtin_bit_cast(u32, f);
  return (u + 0x7FFFu + ((u >> 16) & 1u)) >> 16;
}
__device__ __forceinline__ u32 pack2(float lo, float hi) {
  return f2bf(lo) | (f2bf(hi) << 16);
}
__device__ __forceinline__ void load16_lds(const void* g, void* l) {
  __builtin_amdgcn_global_load_lds((gptr_t)g, (lptr_t)l, 16, 0, 0);
}

// ---------------- setup (atomic-free CSR build; r13 verified) ----------------
__global__ void init_bcur_kernel(int* __restrict__ bcur) {
  if (threadIdx.x < 8) bcur[threadIdx.x] = threadIdx.x * BCAP;
}

__global__ __launch_bounds__(256) void bucket_scatter_kernel(
    const int* __restrict__ src, const int* __restrict__ dst,
    int* __restrict__ bcur, int* __restrict__ es_src, int* __restrict__ es_dst) {
  __shared__ int osrc[EPB];
  __shared__ int odst[EPB];
  __shared__ int h[8], lo8[8], gbase[8], c2[8];
  const int t = threadIdx.x;
  if (t < 8) { h[t] = 0; c2[t] = 0; }
  __syncthreads();
  const int e0 = blockIdx.x * EPB;
  for (int i = t; i < EPB; i += 256) {
    int d = dst[e0 + i];
    atomicAdd(&h[d / GRP], 1);
  }
  __syncthreads();
  if (t == 0) { int r = 0; for (int b = 0; b < 8; ++b) { lo8[b] = r; r += h[b]; } }
  __syncthreads();
  if (t < 8) gbase[t] = atomicAdd(&bcur[t], h[t]);
  __syncthreads();
  for (int i = t; i < EPB; i += 256) {
    int s = src[e0 + i], d = dst[e0 + i];
    int b = d / GRP;
    int p = lo8[b] + atomicAdd(&c2[b], 1);
    osrc[p] = s; odst[p] = d;
  }
  __syncthreads();
  for (int i = t; i < EPB; i += 256) {
    int b = 0;
    while (b < 7 && i >= lo8[b + 1]) ++b;
    int g = gbase[b] + (i - lo8[b]);
    es_src[g] = osrc[i];
    es_dst[g] = odst[i];
  }
}

__global__ __launch_bounds__(256) void hist_part_kernel(
    const int* __restrict__ es_dst, const int* __restrict__ bcur,
    int* __restrict__ part) {
  __shared__ int h[GRP];
  const int g = blockIdx.x >> 5;
  const int s = blockIdx.x & 31;
  const int lo = g * GRP;
  const int base = g * BCAP;
  const int n = bcur[g] - base;
  const int chunk = (n + 31) >> 5;
  const int i0 = s * chunk;
  int i1 = i0 + chunk; if (i1 > n) i1 = n;
  for (int i = threadIdx.x; i < GRP; i += 256) h[i] = 0;
  __syncthreads();
  for (int i = i0 + threadIdx.x; i < i1; i += 256)
    atomicAdd(&h[es_dst[base + i] - lo], 1);  // LDS atomic
  __syncthreads();
  int* po = part + (size_t)blockIdx.x * GRP;
  for (int i = threadIdx.x; i < GRP; i += 256) po[i] = h[i];
}

__global__ void reduce_kernel(int* __restrict__ part, int* __restrict__ cnt) {
  int r = blockIdx.x * 256 + threadIdx.x;
  if (r >= NN) return;
  int g = r / GRP, o = r - g * GRP;
  int* p = part + (size_t)(g * 32) * GRP + o;
  int run = 0;
#pragma unroll
  for (int s = 0; s < 32; ++s) {
    int v = p[(size_t)s * GRP];
    p[(size_t)s * GRP] = run;
    run += v;
  }
  cnt[r] = run;
}

__global__ void scan_kernel(const int* __restrict__ cnt, int* __restrict__ row_start) {
  __shared__ int wsum[4];
  const int CH = 196;
  int t = threadIdx.x;
  int lo = t * CH;
  int hi = lo + CH; if (hi > NN) hi = NN;
  int s = 0;
  int n4 = (hi - lo) >> 2;
  const int4* p = (const int4*)(cnt + lo);
  for (int i = 0; i < n4; ++i) { int4 c = p[i]; s += c.x + c.y + c.z + c.w; }
  int lane = t & 63, w = t >> 6;
  int v = s;
  for (int d = 1; d < 64; d <<= 1) { int u = __shfl_up(v, d, 64); if (lane >= d) v += u; }
  if (lane == 63) wsum[w] = v;
  __syncthreads();
  int run = v - s;
  for (int i = 0; i < w; ++i) run += wsum[i];
  int4* q1 = (int4*)(row_start + lo);
  for (int k = 0; k < n4; ++k) {
    int4 c = p[k];
    int4 o; o.x = run; o.y = run + c.x; o.z = o.y + c.y; o.w = o.z + c.z;
    run = o.w + c.w;
    q1[k] = o;
  }
  if (hi == NN && lo < NN) row_start[NN] = run;
}

__global__ __launch_bounds__(256) void scatter4_kernel(
    const int* __restrict__ es_src, const int* __restrict__ es_dst,
    const int* __restrict__ bcur, const int* __restrict__ row_start,
    const int* __restrict__ part, int* __restrict__ col) {
  __shared__ int cur[GRP];
  const int g = blockIdx.x >> 5;
  const int s = blockIdx.x & 31;
  const int lo = g * GRP;
  const int base = g * BCAP;
  const int n = bcur[g] - base;
  const int chunk = (n + 31) >> 5;
  const int i0 = s * chunk;
  int i1 = i0 + chunk; if (i1 > n) i1 = n;
  const int* po = part + (size_t)blockIdx.x * GRP;
  for (int i = threadIdx.x; i < GRP; i += 256)
    cur[i] = row_start[lo + i] + po[i];
  __syncthreads();
  for (int i = i0 + threadIdx.x; i < i1; i += 256) {
    int d = es_dst[base + i];
    int p = atomicAdd(&cur[d - lo], 1);  // LDS atomic
    col[p] = es_src[base + i];
  }
}

// ---------------- converts ----------------
__global__ void convert_x_kernel(const float* __restrict__ xin, u16* __restrict__ xout) {
  size_t i = ((size_t)blockIdx.x * 256 + threadIdx.x) * 4;
  if (i >= (size_t)NN * FF) return;
  float4 f = *(const float4*)(xin + i);
  u32 o0 = pack2(f.x, f.y);
  u32 o1 = pack2(f.z, f.w);
  u32* q = (u32*)(xout + i);
  q[0] = o0; q[1] = o1;
}

// Bt[n][k] (384 x 768 bf16, row-major): k<384 -> W_rel[n][k], else W_root[n][k-384]
__global__ void build_bt_kernel(const float* __restrict__ Wr, const float* __restrict__ Wt,
                                u16* __restrict__ Bt) {
  int i = blockIdx.x * 256 + threadIdx.x;
  if (i >= FF * 2 * FF) return;
  int n = i / (2 * FF);
  int k = i - n * (2 * FF);
  float v = (k < FF) ? Wr[n * FF + k] : Wt[n * FF + (k - FF)];
  Bt[i] = (u16)f2bf(v);
}

// ---------------- SpMM: agg[dst] = sum_src x[src], feature-split x3 ----------------
// r13 structure (best measured); ONE change: 16-edge unroll (16 gathers in
// flight/wave vs 8) to probe the MLP vs path-saturation question.
__global__ void spmm_pass_kernel(const u16* __restrict__ x, const int* __restrict__ rs,
                                 const int* __restrict__ col, u16* __restrict__ agg,
                                 const int fo) {
  int row = blockIdx.x * 4 + (threadIdx.x >> 6);
  int lane = threadIdx.x & 63;
  if (row >= NN) return;
  int j0 = rs[row], j1 = rs[row + 1];
  float alo = 0.f, ahi = 0.f;
  const u32* xw = (const u32*)x + fo + lane;
  int j = j0;
  for (; j + 16 <= j1; j += 16) {
    int s0 = col[j + 0], s1 = col[j + 1], s2 = col[j + 2], s3 = col[j + 3];
    int s4 = col[j + 4], s5 = col[j + 5], s6 = col[j + 6], s7 = col[j + 7];
    int s8 = col[j + 8], s9 = col[j + 9], sa = col[j + 10], sb = col[j + 11];
    int sc = col[j + 12], sd = col[j + 13], se = col[j + 14], sf = col[j + 15];
    u32 u0 = xw[(size_t)s0 * 192];
    u32 u1 = xw[(size_t)s1 * 192];
    u32 u2 = xw[(size_t)s2 * 192];
    u32 u3 = xw[(size_t)s3 * 192];
    u32 u4 = xw[(size_t)s4 * 192];
    u32 u5 = xw[(size_t)s5 * 192];
    u32 u6 = xw[(size_t)s6 * 192];
    u32 u7 = xw[(size_t)s7 * 192];
    u32 u8 = xw[(size_t)s8 * 192];
    u32 u9 = xw[(size_t)s9 * 192];
    u32 ua = xw[(size_t)sa * 192];
    u32 ub = xw[(size_t)sb * 192];
    u32 uc = xw[(size_t)sc * 192];
    u32 ud = xw[(size_t)sd * 192];
    u32 ue = xw[(size_t)se * 192];
    u32 uf = xw[(size_t)sf * 192];
    alo += bf_lo(u0) + bf_lo(u1) + bf_lo(u2) + bf_lo(u3) +
           bf_lo(u4) + bf_lo(u5) + bf_lo(u6) + bf_lo(u7) +
           bf_lo(u8) + bf_lo(u9) + bf_lo(ua) + bf_lo(ub) +
           bf_lo(uc) + bf_lo(ud) + bf_lo(ue) + bf_lo(uf);
    ahi += bf_hi(u0) + bf_hi(u1) + bf_hi(u2) + bf_hi(u3) +
           bf_hi(u4) + bf_hi(u5) + bf_hi(u6) + bf_hi(u7) +
           bf_hi(u8) + bf_hi(u9) + bf_hi(ua) + bf_hi(ub) +
           bf_hi(uc) + bf_hi(ud) + bf_hi(ue) + bf_hi(uf);
  }
  for (; j < j1; ++j) {
    u32 u = xw[(size_t)col[j] * 192];
    alo += bf_lo(u); ahi += bf_hi(u);
  }
  ((u32*)agg)[(size_t)row * 192 + fo + lane] = pack2(alo, ahi);
}

// ---------------- GEMM: Xout = relu([agg | x] @ Bt^T) ----------------
// bf16 in/out, fp32 accum. BM=64, BN=384 (full N -> A staged ONCE).
// 512 threads = 8 waves (2m x 4n), wave tile 32x96, acc[2][6] = 48 VGPR.
// A: LDS dbuf 2x8KB; B: LDS single 48KB (coalesced global_load_lds w16,
// XOR swizzle both). grid = 782 blocks, bijective XCD swizzle.
__global__ __launch_bounds__(512, 4) void gemm_kernel(
    const u16* __restrict__ Aagg, const u16* __restrict__ Ax,
    const u16* __restrict__ Bt, u16* __restrict__ Xout) {
  __shared__ __align__(16) u16 As[2][64 * 64];
  __shared__ __align__(16) u16 Bs[384 * 64];

  // bijective XCD swizzle: nwg=782, q=97, r=6
  const int orig = blockIdx.x;
  const int xcd = orig & 7, idx = orig >> 3;
  const int wg = ((xcd < 6) ? xcd * 98 : 6 * 98 + (xcd - 6) * 97) + idx;
  const int m0 = wg * 64;

  const int tid = threadIdx.x;
  const int lane = tid & 63;
  const int w = tid >> 6;        // 0..7
  const int wr = w >> 2;         // 0..1  (32-row half)
  const int wc = w & 3;          // 0..3  (96-col group)

  f32x4 acc[2][6] = {};

#define STAGE_A(KT, BUF)                                                        \
  {                                                                             \
    const u16* Asrc_ = ((KT) < 6) ? Aagg : Ax;                                  \
    const int kbA_ = (((KT) < 6) ? (KT) : (KT)-6) << 7;                         \
    const int rA_ = tid >> 3;                                                   \
    const int bcA_ = (tid & 7) << 4;                                            \
    load16_lds((const char*)Asrc_ + (size_t)(m0 + rA_) * 768 + kbA_ +           \
                   (bcA_ ^ ((rA_ & 7) << 4)),                                   \
               (char*)&As[BUF][0] + tid * 16);                                  \
  }

#define STAGE_B(KT)                                                             \
  {                                                                             \
    const int kbB_ = (KT) << 7;                                                 \
    _Pragma("unroll")                                                           \
    for (int i = 0; i < 6; ++i) {                                               \
      const int c = tid + i * 512;                                              \
      const int rB_ = c >> 3;                                                   \
      const int bcB_ = (c & 7) << 4;                                            \
      load16_lds((const char*)Bt + (size_t)rB_ * 1536 + kbB_ +                  \
                     (bcB_ ^ ((rB_ & 7) << 4)),                                 \
                 (char*)&Bs[0] + c * 16);                                       \
    }                                                                           \
  }

  STAGE_A(0, 0);
  STAGE_B(0);
  __syncthreads();

  int buf = 0;
  for (int kt = 0; kt < 12; ++kt) {
    if (kt < 11) STAGE_A(kt + 1, buf ^ 1);  // A prefetch overlaps compute
#pragma unroll
    for (int ks = 0; ks < 2; ++ks) {
      short8 af[2], bfm[6];
#pragma unroll
      for (int ni = 0; ni < 6; ++ni) {
        const int r = wc * 96 + ni * 16 + (lane & 15);
        const int bc = (ks * 64 + ((lane >> 4) << 4)) ^ ((r & 7) << 4);
        bfm[ni] = *(const short8*)((const char*)&Bs[0] + r * 128 + bc);
      }
#pragma unroll
      for (int mi = 0; mi < 2; ++mi) {
        const int r = wr * 32 + mi * 16 + (lane & 15);
        const int bc = (ks * 64 + ((lane >> 4) << 4)) ^ ((r & 7) << 4);
        af[mi] = *(const short8*)((const char*)&As[buf][0] + r * 128 + bc);
      }
#pragma unroll
      for (int mi = 0; mi < 2; ++mi)
#pragma unroll
        for (int ni = 0; ni < 6; ++ni)
          acc[mi][ni] = __builtin_amdgcn_mfma_f32_16x16x32_bf16(af[mi], bfm[ni], acc[mi][ni], 0, 0, 0);
    }
    __syncthreads();  // all waves done reading Bs + As[buf]; drains A prefetch
    if (kt < 11) {
      STAGE_B(kt + 1);
      __syncthreads();  // B(kt+1) ready (sibling block hides this drain)
    }
    buf ^= 1;
  }

  // epilogue: relu -> bf16. D layout: col = lane&15, row = (lane>>4)*4 + reg (m89-verified)
#pragma unroll
  for (int mi = 0; mi < 2; ++mi) {
#pragma unroll
    for (int r = 0; r < 4; ++r) {
      const int row = m0 + wr * 32 + mi * 16 + ((lane >> 4) << 2) + r;
      u16* orow = Xout + (size_t)row * FF + wc * 96 + (lane & 15);
#pragma unroll
      for (int ni = 0; ni < 6; ++ni) {
        float v = fmaxf(acc[mi][ni][r], 0.0f);
        orow[ni * 16] = (u16)f2bf(v);
      }
    }
  }
#undef STAGE_A
#undef STAGE_B
}

// ---------------- readout: out[n] = dot(x[n,:], W_lin) ----------------
__global__ void readout_kernel(const u16* __restrict__ x, const float* __restrict__ wl,
                               float* __restrict__ out) {
  int row = blockIdx.x * 4 + (threadIdx.x >> 6);
  int lane = threadIdx.x & 63;
  if (row >= NN) return;
  const u32* p = (const u32*)(x + (size_t)row * FF) + lane * 3;
  u32 u0 = p[0], u1 = p[1], u2 = p[2];
  const float* w = wl + lane * 6;
  float s = bf_lo(u0) * w[0] + bf_hi(u0) * w[1] +
            bf_lo(u1) * w[2] + bf_hi(u1) * w[3] +
            bf_lo(u2) * w[4] + bf_hi(u2) * w[5];
#pragma unroll
  for (int off = 32; off > 0; off >>= 1) s += __shfl_down(s, off, 64);
  if (lane == 0) out[row] = s;
}

extern "C" void kernel_launch(void* const* d_in, const int* in_sizes, int n_in,
                              void* d_out, int out_size, void* d_ws, size_t ws_size,
                              hipStream_t stream) {
  const float* x_in = (const float*)d_in[0];
  const int* ei = (const int*)d_in[1];
  const float* W_rel = (const float*)d_in[3];
  const float* W_root = (const float*)d_in[4];
  const float* W_lin = (const float*)d_in[5];
  float* out = (float*)d_out;

  char* ws = (char*)d_ws;
  int* cnt = (int*)(ws);                      // 200,000 B used (+64 spare)
  int* bcur = cnt + NN;                       // 8 ints in the spare
  int* row_start = (int*)(ws + 200064);       // 200,064 B
  int* col = (int*)(ws + 600192);             // 6,400,000 B
  u16* Bt = (u16*)(ws + 7000192);             // 589,824 B
  u16* agg = (u16*)(ws + 7590016);            // 38,436,864 B
  u16* x0 = (u16*)(ws + 46026880);            // 38,436,864 B
  u16* x1 = (u16*)(ws + 84463744);            // 38,436,864 B
  if (ws_size < (size_t)122900608) return;    // need ~117 MB
  // transient setup arrays overlay agg (dead before first spmm write):
  int* es_src = (int*)(ws + 7590016);               // 7,040,000 B
  int* es_dst = (int*)(ws + 7590016 + 7040000);     // 7,040,000 B
  int* part = (int*)(ws + 7590016 + 14080000);      // 6,400,000 B

  const int* esrc = ei;
  const int* edst = ei + EE;

  // zero pad rows once per launch (GEMM reads them; pad outputs are row-local)
  hipMemsetAsync(agg + (size_t)NN * FF, 0, (size_t)(MPAD - NN) * FF * sizeof(u16), stream);
  hipMemsetAsync(x0 + (size_t)NN * FF, 0, (size_t)(MPAD - NN) * FF * sizeof(u16), stream);
  hipMemsetAsync(x1 + (size_t)NN * FF, 0, (size_t)(MPAD - NN) * FF * sizeof(u16), stream);

  init_bcur_kernel<<<1, 64, 0, stream>>>(bcur);
  bucket_scatter_kernel<<<EE / EPB, 256, 0, stream>>>(esrc, edst, bcur, es_src, es_dst);
  hist_part_kernel<<<256, 256, 0, stream>>>(es_dst, bcur, part);
  reduce_kernel<<<(NN + 255) / 256, 256, 0, stream>>>(part, cnt);
  scan_kernel<<<1, 256, 0, stream>>>(cnt, row_start);
  scatter4_kernel<<<256, 256, 0, stream>>>(es_src, es_dst, bcur, row_start, part, col);
  convert_x_kernel<<<(NN * FF / 4 + 255) / 256, 256, 0, stream>>>(x_in, x0);
  build_bt_kernel<<<(FF * 2 * FF + 255) / 256, 256, 0, stream>>>(W_rel, W_root, Bt);

  u16* xs = x0;
  u16* xd = x1;
  for (int t = 0; t < NITER; ++t) {
    for (int p = 0; p < 3; ++p)
      spmm_pass_kernel<<<NN / 4, 256, 0, stream>>>(xs, row_start, col, agg, p * 64);
    gemm_kernel<<<MPAD / 64, 512, 0, stream>>>(agg, xs, Bt, xd);
    u16* tmp = xs; xs = xd; xd = tmp;
  }
  readout_kernel<<<NN / 4, 256, 0, stream>>>(xs, W_lin, out);
}

// Round 17
// 1132.796 us; speedup vs baseline: 1.8171x; 1.1145x over previous
//
#include <hip/hip_runtime.h>
#include <hip/hip_bf16.h>

#define NN 50000
#define EE 1600000
#define FF 384
#define MPAD 50048
#define NITER 5
#define EPB 6250      // edges per block in bucket_scatter
#define BCAP 220000   // bucket capacity (mean 200000, +47 sigma)
#define GRP 6250      // rows per dst-group (NN/8)

typedef unsigned int u32;
typedef unsigned short u16;
typedef __attribute__((ext_vector_type(8))) short short8;
typedef __attribute__((ext_vector_type(4))) float f32x4;

typedef const __attribute__((address_space(1))) void* gptr_t;
typedef __attribute__((address_space(3))) void* lptr_t;

__device__ __forceinline__ float bf_lo(u32 u) {
  u32 v = u << 16;
  return __builtin_bit_cast(float, v);
}
__device__ __forceinline__ float bf_hi(u32 u) {
  u32 v = u & 0xFFFF0000u;
  return __builtin_bit_cast(float, v);
}
__device__ __forceinline__ u32 f2bf(float f) {  // RNE f32 -> bf16 bits
  u32 u = __builtin_bit_cast(u32, f);
  return (u + 0x7FFFu + ((u >> 16) & 1u)) >> 16;
}
__device__ __forceinline__ u32 pack2(float lo, float hi) {
  return f2bf(lo) | (f2bf(hi) << 16);
}
__device__ __forceinline__ void load16_lds(const void* g, void* l) {
  __builtin_amdgcn_global_load_lds((gptr_t)g, (lptr_t)l, 16, 0, 0);
}

// ---------------- setup (atomic-free CSR build; r13 verified) ----------------
__global__ void init_bcur_kernel(int* __restrict__ bcur) {
  if (threadIdx.x < 8) bcur[threadIdx.x] = threadIdx.x * BCAP;
}

__global__ __launch_bounds__(256) void bucket_scatter_kernel(
    const int* __restrict__ src, const int* __restrict__ dst,
    int* __restrict__ bcur, int* __restrict__ es_src, int* __restrict__ es_dst) {
  __shared__ int osrc[EPB];
  __shared__ int odst[EPB];
  __shared__ int h[8], lo8[8], gbase[8], c2[8];
  const int t = threadIdx.x;
  if (t < 8) { h[t] = 0; c2[t] = 0; }
  __syncthreads();
  const int e0 = blockIdx.x * EPB;
  for (int i = t; i < EPB; i += 256) {
    int d = dst[e0 + i];
    atomicAdd(&h[d / GRP], 1);
  }
  __syncthreads();
  if (t == 0) { int r = 0; for (int b = 0; b < 8; ++b) { lo8[b] = r; r += h[b]; } }
  __syncthreads();
  if (t < 8) gbase[t] = atomicAdd(&bcur[t], h[t]);
  __syncthreads();
  for (int i = t; i < EPB; i += 256) {
    int s = src[e0 + i], d = dst[e0 + i];
    int b = d / GRP;
    int p = lo8[b] + atomicAdd(&c2[b], 1);
    osrc[p] = s; odst[p] = d;
  }
  __syncthreads();
  for (int i = t; i < EPB; i += 256) {
    int b = 0;
    while (b < 7 && i >= lo8[b + 1]) ++b;
    int g = gbase[b] + (i - lo8[b]);
    es_src[g] = osrc[i];
    es_dst[g] = odst[i];
  }
}

__global__ __launch_bounds__(256) void hist_part_kernel(
    const int* __restrict__ es_dst, const int* __restrict__ bcur,
    int* __restrict__ part) {
  __shared__ int h[GRP];
  const int g = blockIdx.x >> 5;
  const int s = blockIdx.x & 31;
  const int lo = g * GRP;
  const int base = g * BCAP;
  const int n = bcur[g] - base;
  const int chunk = (n + 31) >> 5;
  const int i0 = s * chunk;
  int i1 = i0 + chunk; if (i1 > n) i1 = n;
  for (int i = threadIdx.x; i < GRP; i += 256) h[i] = 0;
  __syncthreads();
  for (int i = i0 + threadIdx.x; i < i1; i += 256)
    atomicAdd(&h[es_dst[base + i] - lo], 1);  // LDS atomic
  __syncthreads();
  int* po = part + (size_t)blockIdx.x * GRP;
  for (int i = threadIdx.x; i < GRP; i += 256) po[i] = h[i];
}

__global__ void reduce_kernel(int* __restrict__ part, int* __restrict__ cnt) {
  int r = blockIdx.x * 256 + threadIdx.x;
  if (r >= NN) return;
  int g = r / GRP, o = r - g * GRP;
  int* p = part + (size_t)(g * 32) * GRP + o;
  int run = 0;
#pragma unroll
  for (int s = 0; s < 32; ++s) {
    int v = p[(size_t)s * GRP];
    p[(size_t)s * GRP] = run;
    run += v;
  }
  cnt[r] = run;
}

__global__ void scan_kernel(const int* __restrict__ cnt, int* __restrict__ row_start) {
  __shared__ int wsum[4];
  const int CH = 196;
  int t = threadIdx.x;
  int lo = t * CH;
  int hi = lo + CH; if (hi > NN) hi = NN;
  int s = 0;
  int n4 = (hi - lo) >> 2;
  const int4* p = (const int4*)(cnt + lo);
  for (int i = 0; i < n4; ++i) { int4 c = p[i]; s += c.x + c.y + c.z + c.w; }
  int lane = t & 63, w = t >> 6;
  int v = s;
  for (int d = 1; d < 64; d <<= 1) { int u = __shfl_up(v, d, 64); if (lane >= d) v += u; }
  if (lane == 63) wsum[w] = v;
  __syncthreads();
  int run = v - s;
  for (int i = 0; i < w; ++i) run += wsum[i];
  int4* q1 = (int4*)(row_start + lo);
  for (int k = 0; k < n4; ++k) {
    int4 c = p[k];
    int4 o; o.x = run; o.y = run + c.x; o.z = o.y + c.y; o.w = o.z + c.z;
    run = o.w + c.w;
    q1[k] = o;
  }
  if (hi == NN && lo < NN) row_start[NN] = run;
}

__global__ __launch_bounds__(256) void scatter4_kernel(
    const int* __restrict__ es_src, const int* __restrict__ es_dst,
    const int* __restrict__ bcur, const int* __restrict__ row_start,
    const int* __restrict__ part, int* __restrict__ col) {
  __shared__ int cur[GRP];
  const int g = blockIdx.x >> 5;
  const int s = blockIdx.x & 31;
  const int lo = g * GRP;
  const int base = g * BCAP;
  const int n = bcur[g] - base;
  const int chunk = (n + 31) >> 5;
  const int i0 = s * chunk;
  int i1 = i0 + chunk; if (i1 > n) i1 = n;
  const int* po = part + (size_t)blockIdx.x * GRP;
  for (int i = threadIdx.x; i < GRP; i += 256)
    cur[i] = row_start[lo + i] + po[i];
  __syncthreads();
  for (int i = i0 + threadIdx.x; i < i1; i += 256) {
    int d = es_dst[base + i];
    int p = atomicAdd(&cur[d - lo], 1);  // LDS atomic
    col[p] = es_src[base + i];
  }
}

// ---------------- converts ----------------
__global__ void convert_x_kernel(const float* __restrict__ xin, u16* __restrict__ xout) {
  size_t i = ((size_t)blockIdx.x * 256 + threadIdx.x) * 4;
  if (i >= (size_t)NN * FF) return;
  float4 f = *(const float4*)(xin + i);
  u32 o0 = pack2(f.x, f.y);
  u32 o1 = pack2(f.z, f.w);
  u32* q = (u32*)(xout + i);
  q[0] = o0; q[1] = o1;
}

// Bt[n][k] (384 x 768 bf16, row-major): k<384 -> W_rel[n][k], else W_root[n][k-384]
__global__ void build_bt_kernel(const float* __restrict__ Wr, const float* __restrict__ Wt,
                                u16* __restrict__ Bt) {
  int i = blockIdx.x * 256 + threadIdx.x;
  if (i >= FF * 2 * FF) return;
  int n = i / (2 * FF);
  int k = i - n * (2 * FF);
  float v = (k < FF) ? Wr[n * FF + k] : Wt[n * FF + (k - FF)];
  Bt[i] = (u16)f2bf(v);
}

// ---------------- SpMM: agg[dst] = sum_src x[src], feature-split x3 (r13 exact) ----------------
__global__ void spmm_pass_kernel(const u16* __restrict__ x, const int* __restrict__ rs,
                                 const int* __restrict__ col, u16* __restrict__ agg,
                                 const int fo) {
  int row = blockIdx.x * 4 + (threadIdx.x >> 6);
  int lane = threadIdx.x & 63;
  if (row >= NN) return;
  int j0 = rs[row], j1 = rs[row + 1];
  float alo = 0.f, ahi = 0.f;
  const u32* xw = (const u32*)x + fo + lane;
  int j = j0;
  for (; j + 8 <= j1; j += 8) {
    int s0 = col[j + 0], s1 = col[j + 1], s2 = col[j + 2], s3 = col[j + 3];
    int s4 = col[j + 4], s5 = col[j + 5], s6 = col[j + 6], s7 = col[j + 7];
    u32 u0 = xw[(size_t)s0 * 192];
    u32 u1 = xw[(size_t)s1 * 192];
    u32 u2 = xw[(size_t)s2 * 192];
    u32 u3 = xw[(size_t)s3 * 192];
    u32 u4 = xw[(size_t)s4 * 192];
    u32 u5 = xw[(size_t)s5 * 192];
    u32 u6 = xw[(size_t)s6 * 192];
    u32 u7 = xw[(size_t)s7 * 192];
    alo += bf_lo(u0) + bf_lo(u1) + bf_lo(u2) + bf_lo(u3) +
           bf_lo(u4) + bf_lo(u5) + bf_lo(u6) + bf_lo(u7);
    ahi += bf_hi(u0) + bf_hi(u1) + bf_hi(u2) + bf_hi(u3) +
           bf_hi(u4) + bf_hi(u5) + bf_hi(u6) + bf_hi(u7);
  }
  for (; j < j1; ++j) {
    u32 u = xw[(size_t)col[j] * 192];
    alo += bf_lo(u); ahi += bf_hi(u);
  }
  ((u32*)agg)[(size_t)row * 192 + fo + lane] = pack2(alo, ahi);
}

// ---------------- GEMM: Xout = relu([agg | x] @ Bt^T) ----------------
// bf16 in/out, fp32 accum. BM=64, BN=384 (full N -> A staged ONCE).
// 512 threads = 8 waves (2m x 4n), wave tile 32x96, acc[2][6] = 48 VGPR.
// A: LDS dbuf 2x8KB; B: LDS single 48KB (coalesced global_load_lds w16,
// XOR swizzle both). grid = 782 blocks, bijective XCD swizzle.
__global__ __launch_bounds__(512, 4) void gemm_kernel(
    const u16* __restrict__ Aagg, const u16* __restrict__ Ax,
    const u16* __restrict__ Bt, u16* __restrict__ Xout) {
  __shared__ __align__(16) u16 As[2][64 * 64];
  __shared__ __align__(16) u16 Bs[384 * 64];

  // bijective XCD swizzle: nwg=782, q=97, r=6
  const int orig = blockIdx.x;
  const int xcd = orig & 7, idx = orig >> 3;
  const int wg = ((xcd < 6) ? xcd * 98 : 6 * 98 + (xcd - 6) * 97) + idx;
  const int m0 = wg * 64;

  const int tid = threadIdx.x;
  const int lane = tid & 63;
  const int w = tid >> 6;        // 0..7
  const int wr = w >> 2;         // 0..1  (32-row half)
  const int wc = w & 3;          // 0..3  (96-col group)

  f32x4 acc[2][6] = {};

#define STAGE_A(KT, BUF)                                                        \
  {                                                                             \
    const u16* Asrc_ = ((KT) < 6) ? Aagg : Ax;                                  \
    const int kbA_ = (((KT) < 6) ? (KT) : (KT)-6) << 7;                         \
    const int rA_ = tid >> 3;                                                   \
    const int bcA_ = (tid & 7) << 4;                                            \
    load16_lds((const char*)Asrc_ + (size_t)(m0 + rA_) * 768 + kbA_ +           \
                   (bcA_ ^ ((rA_ & 7) << 4)),                                   \
               (char*)&As[BUF][0] + tid * 16);                                  \
  }

#define STAGE_B(KT)                                                             \
  {                                                                             \
    const int kbB_ = (KT) << 7;                                                 \
    _Pragma("unroll")                                                           \
    for (int i = 0; i < 6; ++i) {                                               \
      const int c = tid + i * 512;                                              \
      const int rB_ = c >> 3;                                                   \
      const int bcB_ = (c & 7) << 4;                                            \
      load16_lds((const char*)Bt + (size_t)rB_ * 1536 + kbB_ +                  \
                     (bcB_ ^ ((rB_ & 7) << 4)),                                 \
                 (char*)&Bs[0] + c * 16);                                       \
    }                                                                           \
  }

  STAGE_A(0, 0);
  STAGE_B(0);
  __syncthreads();

  int buf = 0;
  for (int kt = 0; kt < 12; ++kt) {
    if (kt < 11) STAGE_A(kt + 1, buf ^ 1);  // A prefetch overlaps compute
#pragma unroll
    for (int ks = 0; ks < 2; ++ks) {
      short8 af[2], bfm[6];
#pragma unroll
      for (int ni = 0; ni < 6; ++ni) {
        const int r = wc * 96 + ni * 16 + (lane & 15);
        const int bc = (ks * 64 + ((lane >> 4) << 4)) ^ ((r & 7) << 4);
        bfm[ni] = *(const short8*)((const char*)&Bs[0] + r * 128 + bc);
      }
#pragma unroll
      for (int mi = 0; mi < 2; ++mi) {
        const int r = wr * 32 + mi * 16 + (lane & 15);
        const int bc = (ks * 64 + ((lane >> 4) << 4)) ^ ((r & 7) << 4);
        af[mi] = *(const short8*)((const char*)&As[buf][0] + r * 128 + bc);
      }
#pragma unroll
      for (int mi = 0; mi < 2; ++mi)
#pragma unroll
        for (int ni = 0; ni < 6; ++ni)
          acc[mi][ni] = __builtin_amdgcn_mfma_f32_16x16x32_bf16(af[mi], bfm[ni], acc[mi][ni], 0, 0, 0);
    }
    __syncthreads();  // all waves done reading Bs + As[buf]; drains A prefetch
    if (kt < 11) {
      STAGE_B(kt + 1);
      __syncthreads();  // B(kt+1) ready (sibling block hides this drain)
    }
    buf ^= 1;
  }

  // epilogue: relu -> bf16. D layout: col = lane&15, row = (lane>>4)*4 + reg (m89-verified)
#pragma unroll
  for (int mi = 0; mi < 2; ++mi) {
#pragma unroll
    for (int r = 0; r < 4; ++r) {
      const int row = m0 + wr * 32 + mi * 16 + ((lane >> 4) << 2) + r;
      u16* orow = Xout + (size_t)row * FF + wc * 96 + (lane & 15);
#pragma unroll
      for (int ni = 0; ni < 6; ++ni) {
        float v = fmaxf(acc[mi][ni][r], 0.0f);
        orow[ni * 16] = (u16)f2bf(v);
      }
    }
  }
#undef STAGE_A
#undef STAGE_B
}

// ---------------- readout: out[n] = dot(x[n,:], W_lin) ----------------
__global__ void readout_kernel(const u16* __restrict__ x, const float* __restrict__ wl,
                               float* __restrict__ out) {
  int row = blockIdx.x * 4 + (threadIdx.x >> 6);
  int lane = threadIdx.x & 63;
  if (row >= NN) return;
  const u32* p = (const u32*)(x + (size_t)row * FF) + lane * 3;
  u32 u0 = p[0], u1 = p[1], u2 = p[2];
  const float* w = wl + lane * 6;
  float s = bf_lo(u0) * w[0] + bf_hi(u0) * w[1] +
            bf_lo(u1) * w[2] + bf_hi(u1) * w[3] +
            bf_lo(u2) * w[4] + bf_hi(u2) * w[5];
#pragma unroll
  for (int off = 32; off > 0; off >>= 1) s += __shfl_down(s, off, 64);
  if (lane == 0) out[row] = s;
}

extern "C" void kernel_launch(void* const* d_in, const int* in_sizes, int n_in,
                              void* d_out, int out_size, void* d_ws, size_t ws_size,
                              hipStream_t stream) {
  const float* x_in = (const float*)d_in[0];
  const int* ei = (const int*)d_in[1];
  const float* W_rel = (const float*)d_in[3];
  const float* W_root = (const float*)d_in[4];
  const float* W_lin = (const float*)d_in[5];
  float* out = (float*)d_out;

  char* ws = (char*)d_ws;
  int* cnt = (int*)(ws);                      // 200,000 B used (+64 spare)
  int* bcur = cnt + NN;                       // 8 ints in the spare
  int* row_start = (int*)(ws + 200064);       // 200,064 B
  int* col = (int*)(ws + 600192);             // 6,400,000 B
  u16* Bt = (u16*)(ws + 7000192);             // 589,824 B
  u16* agg = (u16*)(ws + 7590016);            // 38,436,864 B
  u16* x0 = (u16*)(ws + 46026880);            // 38,436,864 B
  u16* x1 = (u16*)(ws + 84463744);            // 38,436,864 B
  if (ws_size < (size_t)122900608) return;    // need ~117 MB
  // transient setup arrays overlay agg (dead before first spmm write):
  int* es_src = (int*)(ws + 7590016);               // 7,040,000 B
  int* es_dst = (int*)(ws + 7590016 + 7040000);     // 7,040,000 B
  int* part = (int*)(ws + 7590016 + 14080000);      // 6,400,000 B

  const int* esrc = ei;
  const int* edst = ei + EE;

  // zero pad rows once per launch (GEMM reads them; pad outputs are row-local)
  hipMemsetAsync(agg + (size_t)NN * FF, 0, (size_t)(MPAD - NN) * FF * sizeof(u16), stream);
  hipMemsetAsync(x0 + (size_t)NN * FF, 0, (size_t)(MPAD - NN) * FF * sizeof(u16), stream);
  hipMemsetAsync(x1 + (size_t)NN * FF, 0, (size_t)(MPAD - NN) * FF * sizeof(u16), stream);

  init_bcur_kernel<<<1, 64, 0, stream>>>(bcur);
  bucket_scatter_kernel<<<EE / EPB, 256, 0, stream>>>(esrc, edst, bcur, es_src, es_dst);
  hist_part_kernel<<<256, 256, 0, stream>>>(es_dst, bcur, part);
  reduce_kernel<<<(NN + 255) / 256, 256, 0, stream>>>(part, cnt);
  scan_kernel<<<1, 256, 0, stream>>>(cnt, row_start);
  scatter4_kernel<<<256, 256, 0, stream>>>(es_src, es_dst, bcur, row_start, part, col);
  convert_x_kernel<<<(NN * FF / 4 + 255) / 256, 256, 0, stream>>>(x_in, x0);
  build_bt_kernel<<<(FF * 2 * FF + 255) / 256, 256, 0, stream>>>(W_rel, W_root, Bt);

  u16* xs = x0;
  u16* xd = x1;
  for (int t = 0; t < NITER; ++t) {
    for (int p = 0; p < 3; ++p)
      spmm_pass_kernel<<<NN / 4, 256, 0, stream>>>(xs, row_start, col, agg, p * 64);
    gemm_kernel<<<MPAD / 64, 512, 0, stream>>>(agg, xs, Bt, xd);
    u16* tmp = xs; xs = xd; xd = tmp;
  }
  readout_kernel<<<NN / 4, 256, 0, stream>>>(xs, W_lin, out);
}